// Round 1
// baseline (19885.327 us; speedup 1.0000x reference)
//
#include <hip/hip_runtime.h>
#include <cstddef>

#define LAT 512
#define HID 1024
#define NSLOT 16
#define NB 256
#define HOR 64

__device__ __forceinline__ float sigmoid_f(float x) { return 1.0f / (1.0f + __expf(-x)); }
__device__ __forceinline__ float tanh_f(float x) {
    float e = __expf(2.0f * x);
    return 1.0f - 2.0f / (e + 1.0f);
}

// C[m,n] = act( sum_k A1[m,k]*W1[n,k] (+ sum_k A2[m,k]*W2[n,k]) + bias1[n] + bias2[n] )
// A row-major [M,lda], W row-major [N,ldw] (torch Linear weight: out x in).
// Tiling: 64x64 tile, BK=16, 256 threads, 4x4 per thread.
template<int RELU>
__global__ __launch_bounds__(256)
void gemm_tn(const float* __restrict__ A1, int lda1,
             const float* __restrict__ W1, int ldw1, int K1,
             const float* __restrict__ A2, int lda2,
             const float* __restrict__ W2, int ldw2, int K2,
             const float* __restrict__ bias1, const float* __restrict__ bias2,
             float* __restrict__ C, int ldc,
             float* __restrict__ C2, int ldc2,
             int M, int N)
{
    __shared__ float As[16][64];
    __shared__ float Ws[16][64];
    const int t   = threadIdx.x;
    const int bn0 = blockIdx.x * 64;
    const int bm0 = blockIdx.y * 64;
    const int tx  = t & 15;        // n-subtile
    const int ty  = t >> 4;        // m-subtile
    const int lr  = t >> 2;        // 0..63 tile row for loading
    const int lc  = (t & 3) << 2;  // 0,4,8,12 k-offset for loading

    float acc[4][4] = {};

    for (int src = 0; src < 2; ++src) {
        const float* A = src ? A2 : A1;
        if (!A) continue;
        const float* W = src ? W2 : W1;
        const int lda = src ? lda2 : lda1;
        const int ldw = src ? ldw2 : ldw1;
        const int K   = src ? K2 : K1;
        for (int k0 = 0; k0 < K; k0 += 16) {
            float4 av = make_float4(0.f, 0.f, 0.f, 0.f);
            const int am = bm0 + lr;
            if (am < M) av = *(const float4*)(A + (size_t)am * lda + k0 + lc);
            const float4 wv = *(const float4*)(W + (size_t)(bn0 + lr) * ldw + k0 + lc);
            __syncthreads();
            As[lc + 0][lr] = av.x; As[lc + 1][lr] = av.y;
            As[lc + 2][lr] = av.z; As[lc + 3][lr] = av.w;
            Ws[lc + 0][lr] = wv.x; Ws[lc + 1][lr] = wv.y;
            Ws[lc + 2][lr] = wv.z; Ws[lc + 3][lr] = wv.w;
            __syncthreads();
            #pragma unroll
            for (int kk = 0; kk < 16; ++kk) {
                const float4 a = *(const float4*)&As[kk][ty * 4];
                const float4 b = *(const float4*)&Ws[kk][tx * 4];
                const float ar[4] = {a.x, a.y, a.z, a.w};
                const float br[4] = {b.x, b.y, b.z, b.w};
                #pragma unroll
                for (int i = 0; i < 4; ++i)
                    #pragma unroll
                    for (int j = 0; j < 4; ++j)
                        acc[i][j] = fmaf(ar[i], br[j], acc[i][j]);
            }
        }
    }

    const int n0 = bn0 + tx * 4;
    float bv[4] = {0.f, 0.f, 0.f, 0.f};
    if (bias1) {
        #pragma unroll
        for (int j = 0; j < 4; ++j) bv[j] += bias1[n0 + j];
    }
    if (bias2) {
        #pragma unroll
        for (int j = 0; j < 4; ++j) bv[j] += bias2[n0 + j];
    }
    #pragma unroll
    for (int i = 0; i < 4; ++i) {
        const int m = bm0 + ty * 4 + i;
        if (m < M) {
            float ov[4];
            #pragma unroll
            for (int j = 0; j < 4; ++j) {
                float v = acc[i][j] + bv[j];
                if (RELU) v = fmaxf(v, 0.f);
                ov[j] = v;
            }
            const float4 o = make_float4(ov[0], ov[1], ov[2], ov[3]);
            *(float4*)(C + (size_t)m * ldc + n0) = o;
            if (C2) *(float4*)(C2 + (size_t)m * ldc2 + n0) = o;
        }
    }
}

// One block per batch row: scores over 16 slots, softmax, ctx = w @ v
__global__ __launch_bounds__(256)
void attn_kernel(const float* __restrict__ q, const float* __restrict__ k,
                 const float* __restrict__ v, float* __restrict__ ctx)
{
    __shared__ float red[NSLOT][4];
    __shared__ float wts[NSLOT];
    const int b = blockIdx.x;
    const int t = threadIdx.x;
    const float4 qv = *(const float4*)(q + (size_t)b * HID + t * 4);
    #pragma unroll
    for (int s = 0; s < NSLOT; ++s) {
        const float4 kv = *(const float4*)(k + (size_t)s * HID + t * 4);
        float p = qv.x * kv.x + qv.y * kv.y + qv.z * kv.z + qv.w * kv.w;
        #pragma unroll
        for (int off = 32; off > 0; off >>= 1) p += __shfl_down(p, off);
        if ((t & 63) == 0) red[s][t >> 6] = p;
    }
    __syncthreads();
    if (t == 0) {
        float sc[NSLOT];
        float mx = -1e30f;
        for (int s = 0; s < NSLOT; ++s) {
            sc[s] = (red[s][0] + red[s][1] + red[s][2] + red[s][3]) * 0.03125f;
            mx = fmaxf(mx, sc[s]);
        }
        float sum = 0.f;
        for (int s = 0; s < NSLOT; ++s) { const float e = __expf(sc[s] - mx); wts[s] = e; sum += e; }
        const float inv = 1.f / sum;
        for (int s = 0; s < NSLOT; ++s) wts[s] *= inv;
    }
    __syncthreads();
    float4 a = make_float4(0.f, 0.f, 0.f, 0.f);
    #pragma unroll
    for (int s = 0; s < NSLOT; ++s) {
        const float w = wts[s];
        const float4 vv = *(const float4*)(v + (size_t)s * HID + t * 4);
        a.x += w * vv.x; a.y += w * vv.y; a.z += w * vv.z; a.w += w * vv.w;
    }
    *(float4*)(ctx + (size_t)b * HID + t * 4) = a;
}

// gates [NB, 4*HID] in i|f|g|o order -> update h,c [NB, HID]
__global__ __launch_bounds__(256)
void lstm_pw(const float* __restrict__ gates, float* __restrict__ h, float* __restrict__ c)
{
    const int idx = blockIdx.x * 256 + threadIdx.x;   // < NB*HID
    const int b = idx >> 10;
    const int j = idx & (HID - 1);
    const float* g = gates + ((size_t)b << 12);
    const float i_ = sigmoid_f(g[j]);
    const float f_ = sigmoid_f(g[HID + j]);
    const float g_ = tanh_f(g[2 * HID + j]);
    const float o_ = sigmoid_f(g[3 * HID + j]);
    const float cn = f_ * c[idx] + i_ * g_;
    c[idx] = cn;
    h[idx] = o_ * tanh_f(cn);
}

extern "C" void kernel_launch(void* const* d_in, const int* in_sizes, int n_in,
                              void* d_out, int out_size, void* d_ws, size_t ws_size,
                              hipStream_t stream)
{
    const float* cs    = (const float*)d_in[0];
    // d_in[1] = horizon (fixed 64)
    const float* mem   = (const float*)d_in[2];
    const float* q_W   = (const float*)d_in[3];
    const float* q_b   = (const float*)d_in[4];
    const float* k_W   = (const float*)d_in[5];
    const float* k_b   = (const float*)d_in[6];
    const float* v_W   = (const float*)d_in[7];
    const float* v_b   = (const float*)d_in[8];
    const float* mo_W  = (const float*)d_in[9];
    const float* mo_b  = (const float*)d_in[10];
    const float* pg_W1 = (const float*)d_in[11];
    const float* pg_b1 = (const float*)d_in[12];
    const float* pg_W2 = (const float*)d_in[13];
    const float* pg_b2 = (const float*)d_in[14];
    const float* w_ih0 = (const float*)d_in[15];
    const float* w_hh0 = (const float*)d_in[16];
    const float* b_ih0 = (const float*)d_in[17];
    const float* b_hh0 = (const float*)d_in[18];
    const float* w_ih1 = (const float*)d_in[19];
    const float* w_hh1 = (const float*)d_in[20];
    const float* b_ih1 = (const float*)d_in[21];
    const float* b_hh1 = (const float*)d_in[22];
    const float* op_W1 = (const float*)d_in[23];
    const float* op_b1 = (const float*)d_in[24];
    const float* op_W2 = (const float*)d_in[25];
    const float* op_b2 = (const float*)d_in[26];

    float* out       = (float*)d_out;
    float* prior_out = out + (size_t)NB * HOR * LAT;

    float* p = (float*)d_ws;
    float* xbuf   = p; p += NB * LAT;
    float* h0     = p; p += NB * HID;   // h0,c0,h1,c1 contiguous for one memset
    float* c0     = p; p += NB * HID;
    float* h1     = p; p += NB * HID;
    float* c1     = p; p += NB * HID;
    float* gates  = p; p += NB * 4 * HID;
    float* tbuf   = p; p += NB * HID;
    float* qbuf   = p; p += NB * HID;
    float* kbuf   = p; p += NSLOT * HID;
    float* vbuf   = p; p += NSLOT * HID;
    float* ctxbuf = p; p += NB * HID;
    float* ctxo   = p; p += NB * LAT;
    float* pgh    = p; p += NB * HID;

    hipMemsetAsync(h0, 0, (size_t)4 * NB * HID * sizeof(float), stream);

    const dim3 blk(256);

    // k = memory @ k_W.T + k_b ; v = memory @ v_W.T + v_b      [16, 1024]
    gemm_tn<0><<<dim3(HID / 64, 1), blk, 0, stream>>>(
        mem, HID, k_W, HID, HID, nullptr, 0, nullptr, 0, 0,
        k_b, nullptr, kbuf, HID, nullptr, 0, NSLOT, HID);
    gemm_tn<0><<<dim3(HID / 64, 1), blk, 0, stream>>>(
        mem, HID, v_W, HID, HID, nullptr, 0, nullptr, 0, 0,
        v_b, nullptr, vbuf, HID, nullptr, 0, NSLOT, HID);
    // q = cs @ q_W.T + q_b                                     [256, 1024]
    gemm_tn<0><<<dim3(HID / 64, NB / 64), blk, 0, stream>>>(
        cs, LAT, q_W, LAT, LAT, nullptr, 0, nullptr, 0, 0,
        q_b, nullptr, qbuf, HID, nullptr, 0, NB, HID);
    // softmax attention over 16 slots -> ctx                    [256, 1024]
    attn_kernel<<<dim3(NB), blk, 0, stream>>>(qbuf, kbuf, vbuf, ctxbuf);
    // context = ctx @ mo_W.T + mo_b                             [256, 512]
    gemm_tn<0><<<dim3(LAT / 64, NB / 64), blk, 0, stream>>>(
        ctxbuf, HID, mo_W, HID, HID, nullptr, 0, nullptr, 0, 0,
        mo_b, nullptr, ctxo, LAT, nullptr, 0, NB, LAT);
    // pgh = relu([cs|context] @ pg_W1.T + pg_b1)  (dual-source avoids concat)
    gemm_tn<1><<<dim3(HID / 64, NB / 64), blk, 0, stream>>>(
        cs, LAT, pg_W1, HID, LAT, ctxo, LAT, pg_W1 + LAT, HID, LAT,
        pg_b1, nullptr, pgh, HID, nullptr, 0, NB, HID);
    // prior = pgh @ pg_W2.T + pg_b2 -> prior output AND x0
    gemm_tn<0><<<dim3(LAT / 64, NB / 64), blk, 0, stream>>>(
        pgh, HID, pg_W2, HID, HID, nullptr, 0, nullptr, 0, 0,
        pg_b2, nullptr, prior_out, LAT, xbuf, LAT, NB, LAT);

    for (int step = 0; step < HOR; ++step) {
        // gates0 = x @ w_ih0.T + h0 @ w_hh0.T + b_ih0 + b_hh0   [256, 4096]
        gemm_tn<0><<<dim3(4 * HID / 64, NB / 64), blk, 0, stream>>>(
            xbuf, LAT, w_ih0, LAT, LAT, h0, HID, w_hh0, HID, HID,
            b_ih0, b_hh0, gates, 4 * HID, nullptr, 0, NB, 4 * HID);
        lstm_pw<<<dim3(NB * HID / 256), blk, 0, stream>>>(gates, h0, c0);
        // gates1 = h0 @ w_ih1.T + h1 @ w_hh1.T + b_ih1 + b_hh1  [256, 4096]
        gemm_tn<0><<<dim3(4 * HID / 64, NB / 64), blk, 0, stream>>>(
            h0, HID, w_ih1, HID, HID, h1, HID, w_hh1, HID, HID,
            b_ih1, b_hh1, gates, 4 * HID, nullptr, 0, NB, 4 * HID);
        lstm_pw<<<dim3(NB * HID / 256), blk, 0, stream>>>(gates, h1, c1);
        // t = relu(h1 @ op_W1.T + op_b1)                         [256, 1024]
        gemm_tn<1><<<dim3(HID / 64, NB / 64), blk, 0, stream>>>(
            h1, HID, op_W1, HID, HID, nullptr, 0, nullptr, 0, 0,
            op_b1, nullptr, tbuf, HID, nullptr, 0, NB, HID);
        // pred = t @ op_W2.T + op_b2 -> out[:, step, :] AND next x
        gemm_tn<0><<<dim3(LAT / 64, NB / 64), blk, 0, stream>>>(
            tbuf, HID, op_W2, HID, HID, nullptr, 0, nullptr, 0, 0,
            op_b2, nullptr, out + (size_t)step * LAT, HOR * LAT, xbuf, LAT, NB, LAT);
    }
}

// Round 2
// 4448.263 us; speedup vs baseline: 4.4704x; 4.4704x over previous
//
#include <hip/hip_runtime.h>
#include <cstddef>
#include <cstdint>

#define LAT 512
#define HID 1024
#define NSLOT 16
#define NB 256
#define HOR 64

using short8  = __attribute__((ext_vector_type(8))) short;
using floatx4 = __attribute__((ext_vector_type(4))) float;

__device__ __forceinline__ float sigmoid_f(float x) { return 1.0f / (1.0f + __expf(-x)); }
__device__ __forceinline__ float tanh_f(float x) {
    float e = __expf(2.0f * x);
    return 1.0f - 2.0f / (e + 1.0f);
}
__device__ __forceinline__ unsigned short f2bf(float f) {
    union { float f; uint32_t u; } v; v.f = f;
    uint32_t u = v.u;
    return (unsigned short)((u + 0x7fffu + ((u >> 16) & 1u)) >> 16);
}
// async global->LDS, 16B per lane. LDS dest is wave-uniform base + lane*16.
__device__ __forceinline__ void async16(const void* g, void* l) {
    __builtin_amdgcn_global_load_lds(
        (const __attribute__((address_space(1))) unsigned int*)(unsigned long long)g,
        (__attribute__((address_space(3))) unsigned int*)(unsigned int)(unsigned long long)l,
        16, 0, 0);
}

// ---------------------------------------------------------------------------
// bf16 MFMA GEMM: C[M,N] = A[M,K] * W[N,K]^T  (both K-contiguous bf16)
// Block tile BM x BN, 256 threads = 4 waves (2x2), wave tile BM/2 x BN/2,
// 16x16x32 bf16 MFMA, BK=64, async global_load_lds staging with XOR-chunk
// swizzle (conflict-free ds_read_b128 fragment reads, <=2-way which is free).
// MODE 0: partial fp32 store to Cf + blockIdx.z*zstride (split-K)
// MODE 1: +bias, ReLU, bf16 store to Cb
// MODE 2: +bias, fp32 store to Cf AND bf16 store to Cb
// ---------------------------------------------------------------------------
template<int BM, int BN, int MODE>
__global__ __launch_bounds__(256)
void mfma_gemm(const unsigned short* __restrict__ A, int lda,
               const unsigned short* __restrict__ W, int ldw, int Kc,
               const float* __restrict__ bias,
               float* __restrict__ Cf, int ldc, long long zstride,
               unsigned short* __restrict__ Cb, int ldcb)
{
    constexpr int WM = BM / 2, WN = BN / 2, TM = WM / 16, TN = WN / 16;
    __shared__ __attribute__((aligned(16))) short As[BM * 64];  // BM rows x 8 chunks x 8 bf16
    __shared__ __attribute__((aligned(16))) short Bs[BN * 64];

    const int t    = threadIdx.x;
    const int lane = t & 63;
    const int w    = t >> 6;
    const int wm   = w >> 1, wn = w & 1;
    const int m0   = blockIdx.y * BM;
    const int n0   = blockIdx.x * BN;
    const int kb   = blockIdx.z * Kc;

    // staging: each group of 8 lanes covers one row (8x16B chunks, permuted)
    const int r8 = lane >> 3;
    const int cx = (lane & 7) ^ r8;   // chunk c stored at in-row position c^row -> swizzle

    const int q  = lane >> 4;
    const int ml = lane & 15;

    floatx4 acc[TM][TN];
    const floatx4 zf = {0.f, 0.f, 0.f, 0.f};
    #pragma unroll
    for (int i = 0; i < TM; ++i)
        #pragma unroll
        for (int j = 0; j < TN; ++j) acc[i][j] = zf;

    for (int k0 = kb; k0 < kb + Kc; k0 += 64) {
        __syncthreads();
        #pragma unroll
        for (int u = 0; u < BM / 32; ++u) {
            const int row = w * (BM / 4) + u * 8;
            async16(A + (size_t)(m0 + row + r8) * lda + k0 + cx * 8, &As[row * 64]);
        }
        #pragma unroll
        for (int u = 0; u < BN / 32; ++u) {
            const int row = w * (BN / 4) + u * 8;
            async16(W + (size_t)(n0 + row + r8) * ldw + k0 + cx * 8, &Bs[row * 64]);
        }
        __syncthreads();   // drains vmcnt before barrier -> deposits visible
        #pragma unroll
        for (int s = 0; s < 2; ++s) {
            short8 af[TM], bfr[TN];
            #pragma unroll
            for (int i = 0; i < TM; ++i) {
                const int m = wm * WM + i * 16 + ml;
                af[i] = *(const short8*)&As[(m * 8 + ((s * 4 + q) ^ (m & 7))) * 8];
            }
            #pragma unroll
            for (int j = 0; j < TN; ++j) {
                const int n = wn * WN + j * 16 + ml;
                bfr[j] = *(const short8*)&Bs[(n * 8 + ((s * 4 + q) ^ (n & 7))) * 8];
            }
            #pragma unroll
            for (int i = 0; i < TM; ++i)
                #pragma unroll
                for (int j = 0; j < TN; ++j)
                    acc[i][j] = __builtin_amdgcn_mfma_f32_16x16x32_bf16(af[i], bfr[j], acc[i][j], 0, 0, 0);
        }
    }

    // epilogue: C/D layout col = lane&15, row = q*4 + reg
    const int gmb = m0 + wm * WM + q * 4;
    const int gnb = n0 + wn * WN + ml;
    if (MODE == 0) {
        float* dst = Cf + (long long)blockIdx.z * zstride;
        #pragma unroll
        for (int i = 0; i < TM; ++i)
            #pragma unroll
            for (int j = 0; j < TN; ++j) {
                const int gm = gmb + i * 16, gn = gnb + j * 16;
                #pragma unroll
                for (int r = 0; r < 4; ++r)
                    dst[(size_t)(gm + r) * ldc + gn] = acc[i][j][r];
            }
    } else {
        #pragma unroll
        for (int i = 0; i < TM; ++i)
            #pragma unroll
            for (int j = 0; j < TN; ++j) {
                const int gm = gmb + i * 16, gn = gnb + j * 16;
                const float bv = bias[gn];
                #pragma unroll
                for (int r = 0; r < 4; ++r) {
                    float v = acc[i][j][r] + bv;
                    if (MODE == 1) v = fmaxf(v, 0.f);
                    if (MODE == 2) Cf[(size_t)(gm + r) * ldc + gn] = v;
                    Cb[(size_t)(gm + r) * ldcb + gn] = f2bf(v);
                }
            }
    }
}

// pack fp32 weight(s) into one K-concatenated bf16 matrix: d[n][0:K1]=s1, d[n][K1:K]=s2
__global__ __launch_bounds__(256)
void pack2(const float* __restrict__ s1, int K1, const float* __restrict__ s2, int K2,
           unsigned short* __restrict__ d, int total, int K)
{
    const int idx = blockIdx.x * 256 + threadIdx.x;
    if (idx >= total) return;
    const int n = idx / K;
    const int k = idx - n * K;
    const float v = (k < K1) ? s1[(size_t)n * K1 + k] : s2[(size_t)n * K2 + (k - K1)];
    d[idx] = f2bf(v);
}

// LSTM pointwise: sums 4 split-K partials + both biases, gate order i|f|g|o.
// Writes h (bf16) to one or two strided destinations, c (fp32) in place.
__global__ __launch_bounds__(256)
void lstm_pw4(const float* __restrict__ P, long long zstride,
              const float* __restrict__ b_ih, const float* __restrict__ b_hh,
              float* __restrict__ c,
              unsigned short* __restrict__ h1d, int ld1,
              unsigned short* __restrict__ h2d, int ld2)
{
    const int idx = blockIdx.x * 256 + threadIdx.x;   // < NB*HID
    const int b = idx >> 10;
    const int j = idx & (HID - 1);
    const float* p = P + (size_t)b * (4 * HID) + j;
    float gi = b_ih[j]           + b_hh[j];
    float gf = b_ih[HID + j]     + b_hh[HID + j];
    float gg = b_ih[2 * HID + j] + b_hh[2 * HID + j];
    float go = b_ih[3 * HID + j] + b_hh[3 * HID + j];
    #pragma unroll
    for (int z = 0; z < 4; ++z) {
        const float* pz = p + (long long)z * zstride;
        gi += pz[0]; gf += pz[HID]; gg += pz[2 * HID]; go += pz[3 * HID];
    }
    const float i_ = sigmoid_f(gi), f_ = sigmoid_f(gf);
    const float g_ = tanh_f(gg),    o_ = sigmoid_f(go);
    const float cn = f_ * c[idx] + i_ * g_;
    c[idx] = cn;
    const unsigned short hb = f2bf(o_ * tanh_f(cn));
    h1d[(size_t)b * ld1 + j] = hb;
    if (h2d) h2d[(size_t)b * ld2 + j] = hb;
}

// ---------------------------------------------------------------------------
// fp32 prologue GEMM (attention + prior): small, runs once. C2 = bf16 copy.
// ---------------------------------------------------------------------------
template<int RELU>
__global__ __launch_bounds__(256)
void gemm_tn(const float* __restrict__ A1, int lda1,
             const float* __restrict__ W1, int ldw1, int K1,
             const float* __restrict__ A2, int lda2,
             const float* __restrict__ W2, int ldw2, int K2,
             const float* __restrict__ bias1,
             float* __restrict__ C, int ldc,
             unsigned short* __restrict__ C2, int ldc2,
             int M, int N)
{
    __shared__ float As[16][64];
    __shared__ float Ws[16][64];
    const int t   = threadIdx.x;
    const int bn0 = blockIdx.x * 64;
    const int bm0 = blockIdx.y * 64;
    const int tx  = t & 15;
    const int ty  = t >> 4;
    const int lr  = t >> 2;
    const int lc  = (t & 3) << 2;

    float acc[4][4] = {};

    for (int src = 0; src < 2; ++src) {
        const float* A = src ? A2 : A1;
        if (!A) continue;
        const float* W = src ? W2 : W1;
        const int lda = src ? lda2 : lda1;
        const int ldw = src ? ldw2 : ldw1;
        const int K   = src ? K2 : K1;
        for (int k0 = 0; k0 < K; k0 += 16) {
            float4 av = make_float4(0.f, 0.f, 0.f, 0.f);
            const int am = bm0 + lr;
            if (am < M) av = *(const float4*)(A + (size_t)am * lda + k0 + lc);
            const float4 wv = *(const float4*)(W + (size_t)(bn0 + lr) * ldw + k0 + lc);
            __syncthreads();
            As[lc + 0][lr] = av.x; As[lc + 1][lr] = av.y;
            As[lc + 2][lr] = av.z; As[lc + 3][lr] = av.w;
            Ws[lc + 0][lr] = wv.x; Ws[lc + 1][lr] = wv.y;
            Ws[lc + 2][lr] = wv.z; Ws[lc + 3][lr] = wv.w;
            __syncthreads();
            #pragma unroll
            for (int kk = 0; kk < 16; ++kk) {
                const float4 a = *(const float4*)&As[kk][ty * 4];
                const float4 b = *(const float4*)&Ws[kk][tx * 4];
                const float ar[4] = {a.x, a.y, a.z, a.w};
                const float br[4] = {b.x, b.y, b.z, b.w};
                #pragma unroll
                for (int i = 0; i < 4; ++i)
                    #pragma unroll
                    for (int j = 0; j < 4; ++j)
                        acc[i][j] = fmaf(ar[i], br[j], acc[i][j]);
            }
        }
    }

    const int n0 = bn0 + tx * 4;
    float bv[4] = {0.f, 0.f, 0.f, 0.f};
    if (bias1) {
        #pragma unroll
        for (int j = 0; j < 4; ++j) bv[j] += bias1[n0 + j];
    }
    #pragma unroll
    for (int i = 0; i < 4; ++i) {
        const int m = bm0 + ty * 4 + i;
        if (m < M) {
            float ov[4];
            #pragma unroll
            for (int j = 0; j < 4; ++j) {
                float v = acc[i][j] + bv[j];
                if (RELU) v = fmaxf(v, 0.f);
                ov[j] = v;
            }
            *(float4*)(C + (size_t)m * ldc + n0) = make_float4(ov[0], ov[1], ov[2], ov[3]);
            if (C2) {
                #pragma unroll
                for (int j = 0; j < 4; ++j)
                    C2[(size_t)m * ldc2 + n0 + j] = f2bf(ov[j]);
            }
        }
    }
}

__global__ __launch_bounds__(256)
void attn_kernel(const float* __restrict__ q, const float* __restrict__ k,
                 const float* __restrict__ v, float* __restrict__ ctx)
{
    __shared__ float red[NSLOT][4];
    __shared__ float wts[NSLOT];
    const int b = blockIdx.x;
    const int t = threadIdx.x;
    const float4 qv = *(const float4*)(q + (size_t)b * HID + t * 4);
    #pragma unroll
    for (int s = 0; s < NSLOT; ++s) {
        const float4 kv = *(const float4*)(k + (size_t)s * HID + t * 4);
        float p = qv.x * kv.x + qv.y * kv.y + qv.z * kv.z + qv.w * kv.w;
        #pragma unroll
        for (int off = 32; off > 0; off >>= 1) p += __shfl_down(p, off);
        if ((t & 63) == 0) red[s][t >> 6] = p;
    }
    __syncthreads();
    if (t == 0) {
        float sc[NSLOT];
        float mx = -1e30f;
        for (int s = 0; s < NSLOT; ++s) {
            sc[s] = (red[s][0] + red[s][1] + red[s][2] + red[s][3]) * 0.03125f;
            mx = fmaxf(mx, sc[s]);
        }
        float sum = 0.f;
        for (int s = 0; s < NSLOT; ++s) { const float e = __expf(sc[s] - mx); wts[s] = e; sum += e; }
        const float inv = 1.f / sum;
        for (int s = 0; s < NSLOT; ++s) wts[s] *= inv;
    }
    __syncthreads();
    float4 a = make_float4(0.f, 0.f, 0.f, 0.f);
    #pragma unroll
    for (int s = 0; s < NSLOT; ++s) {
        const float wv = wts[s];
        const float4 vv = *(const float4*)(v + (size_t)s * HID + t * 4);
        a.x += wv * vv.x; a.y += wv * vv.y; a.z += wv * vv.z; a.w += wv * vv.w;
    }
    *(float4*)(ctx + (size_t)b * HID + t * 4) = a;
}

extern "C" void kernel_launch(void* const* d_in, const int* in_sizes, int n_in,
                              void* d_out, int out_size, void* d_ws, size_t ws_size,
                              hipStream_t stream)
{
    const float* cs    = (const float*)d_in[0];
    const float* mem   = (const float*)d_in[2];
    const float* q_W   = (const float*)d_in[3];
    const float* q_b   = (const float*)d_in[4];
    const float* k_W   = (const float*)d_in[5];
    const float* k_b   = (const float*)d_in[6];
    const float* v_W   = (const float*)d_in[7];
    const float* v_b   = (const float*)d_in[8];
    const float* mo_W  = (const float*)d_in[9];
    const float* mo_b  = (const float*)d_in[10];
    const float* pg_W1 = (const float*)d_in[11];
    const float* pg_b1 = (const float*)d_in[12];
    const float* pg_W2 = (const float*)d_in[13];
    const float* pg_b2 = (const float*)d_in[14];
    const float* w_ih0 = (const float*)d_in[15];
    const float* w_hh0 = (const float*)d_in[16];
    const float* b_ih0 = (const float*)d_in[17];
    const float* b_hh0 = (const float*)d_in[18];
    const float* w_ih1 = (const float*)d_in[19];
    const float* w_hh1 = (const float*)d_in[20];
    const float* b_ih1 = (const float*)d_in[21];
    const float* b_hh1 = (const float*)d_in[22];
    const float* op_W1 = (const float*)d_in[23];
    const float* op_b1 = (const float*)d_in[24];
    const float* op_W2 = (const float*)d_in[25];
    const float* op_b2 = (const float*)d_in[26];

    float* out       = (float*)d_out;
    float* prior_out = out + (size_t)NB * HOR * LAT;

    char* base = (char*)d_ws;
    auto alloc = [&](size_t bytes) { char* r = base; base += (bytes + 255) & ~255ull; return r; };

    unsigned short* Wg0 = (unsigned short*)alloc((size_t)4 * HID * (LAT + HID) * 2);  // [4096][1536]
    unsigned short* Wg1 = (unsigned short*)alloc((size_t)4 * HID * (2 * HID) * 2);    // [4096][2048]
    unsigned short* Wo1 = (unsigned short*)alloc((size_t)HID * HID * 2);              // [1024][1024]
    unsigned short* Wo2 = (unsigned short*)alloc((size_t)LAT * HID * 2);              // [512][1024]
    float*          gatesP = (float*)alloc((size_t)4 * NB * 4 * HID * 4);             // 4 partials
    // zero-init region (contiguous: sizes are 256B multiples)
    unsigned short* xh0 = (unsigned short*)alloc((size_t)NB * (LAT + HID) * 2);       // [x | h0]
    unsigned short* hh1 = (unsigned short*)alloc((size_t)NB * (2 * HID) * 2);         // [h0 | h1]
    float*          c0  = (float*)alloc((size_t)NB * HID * 4);
    float*          c1  = (float*)alloc((size_t)NB * HID * 4);
    unsigned short* tbuf = (unsigned short*)alloc((size_t)NB * HID * 2);
    float* qbuf   = (float*)alloc((size_t)NB * HID * 4);
    float* kbuf   = (float*)alloc((size_t)NSLOT * HID * 4);
    float* vbuf   = (float*)alloc((size_t)NSLOT * HID * 4);
    float* ctxbuf = (float*)alloc((size_t)NB * HID * 4);
    float* ctxo   = (float*)alloc((size_t)NB * LAT * 4);
    float* pgh    = (float*)alloc((size_t)NB * HID * 4);

    const size_t zbytes = (size_t)NB * (LAT + HID) * 2 + (size_t)NB * (2 * HID) * 2
                        + (size_t)NB * HID * 4 * 2;
    hipMemsetAsync(xh0, 0, zbytes, stream);

    const dim3 blk(256);

    // ---- pack weights to bf16 (K-concatenated for the gate GEMMs) ----
    {
        int tot = 4 * HID * (LAT + HID);
        pack2<<<dim3((tot + 255) / 256), blk, 0, stream>>>(w_ih0, LAT, w_hh0, HID, Wg0, tot, LAT + HID);
        tot = 4 * HID * (2 * HID);
        pack2<<<dim3((tot + 255) / 256), blk, 0, stream>>>(w_ih1, HID, w_hh1, HID, Wg1, tot, 2 * HID);
        tot = HID * HID;
        pack2<<<dim3((tot + 255) / 256), blk, 0, stream>>>(op_W1, HID, nullptr, 0, Wo1, tot, HID);
        tot = LAT * HID;
        pack2<<<dim3((tot + 255) / 256), blk, 0, stream>>>(op_W2, HID, nullptr, 0, Wo2, tot, HID);
    }

    // ---- prologue (fp32): attention read + prior ----
    gemm_tn<0><<<dim3(HID / 64, 1), blk, 0, stream>>>(
        mem, HID, k_W, HID, HID, nullptr, 0, nullptr, 0, 0,
        k_b, kbuf, HID, nullptr, 0, NSLOT, HID);
    gemm_tn<0><<<dim3(HID / 64, 1), blk, 0, stream>>>(
        mem, HID, v_W, HID, HID, nullptr, 0, nullptr, 0, 0,
        v_b, vbuf, HID, nullptr, 0, NSLOT, HID);
    gemm_tn<0><<<dim3(HID / 64, NB / 64), blk, 0, stream>>>(
        cs, LAT, q_W, LAT, LAT, nullptr, 0, nullptr, 0, 0,
        q_b, qbuf, HID, nullptr, 0, NB, HID);
    attn_kernel<<<dim3(NB), blk, 0, stream>>>(qbuf, kbuf, vbuf, ctxbuf);
    gemm_tn<0><<<dim3(LAT / 64, NB / 64), blk, 0, stream>>>(
        ctxbuf, HID, mo_W, HID, HID, nullptr, 0, nullptr, 0, 0,
        mo_b, ctxo, LAT, nullptr, 0, NB, LAT);
    gemm_tn<1><<<dim3(HID / 64, NB / 64), blk, 0, stream>>>(
        cs, LAT, pg_W1, HID, LAT, ctxo, LAT, pg_W1 + LAT, HID, LAT,
        pg_b1, pgh, HID, nullptr, 0, NB, HID);
    // prior -> fp32 output AND bf16 x0 (first 512 cols of xh0)
    gemm_tn<0><<<dim3(LAT / 64, NB / 64), blk, 0, stream>>>(
        pgh, HID, pg_W2, HID, HID, nullptr, 0, nullptr, 0, 0,
        pg_b2, prior_out, LAT, xh0, LAT + HID, NB, LAT);

    // ---- LSTM rollout ----
    const long long zMN = (long long)NB * 4 * HID;
    for (int step = 0; step < HOR; ++step) {
        // gates0 = [x|h0] @ [w_ih0|w_hh0]^T   (split-K=4, partials)
        mfma_gemm<128, 128, 0><<<dim3(4 * HID / 128, NB / 128, 4), blk, 0, stream>>>(
            xh0, LAT + HID, Wg0, LAT + HID, (LAT + HID) / 4,
            nullptr, gatesP, 4 * HID, zMN, nullptr, 0);
        lstm_pw4<<<dim3(NB * HID / 256), blk, 0, stream>>>(
            gatesP, zMN, b_ih0, b_hh0, c0, xh0 + LAT, LAT + HID, hh1, 2 * HID);
        // gates1 = [h0|h1] @ [w_ih1|w_hh1]^T
        mfma_gemm<128, 128, 0><<<dim3(4 * HID / 128, NB / 128, 4), blk, 0, stream>>>(
            hh1, 2 * HID, Wg1, 2 * HID, (2 * HID) / 4,
            nullptr, gatesP, 4 * HID, zMN, nullptr, 0);
        lstm_pw4<<<dim3(NB * HID / 256), blk, 0, stream>>>(
            gatesP, zMN, b_ih1, b_hh1, c1, hh1 + HID, 2 * HID, nullptr, 0);
        // t = relu(h1 @ op_W1^T + b1) -> bf16
        mfma_gemm<64, 64, 1><<<dim3(HID / 64, NB / 64, 1), blk, 0, stream>>>(
            hh1 + HID, 2 * HID, Wo1, HID, HID,
            op_b1, nullptr, 0, 0, tbuf, HID);
        // pred = t @ op_W2^T + b2 -> fp32 out[:,step,:] AND bf16 next-x
        mfma_gemm<64, 64, 2><<<dim3(LAT / 64, NB / 64, 1), blk, 0, stream>>>(
            tbuf, HID, Wo2, HID, HID,
            op_b2, out + (size_t)step * LAT, HOR * LAT, 0, xh0, LAT + HID);
    }
}